// Round 7
// baseline (63.771 us; speedup 1.0000x reference)
//
#include <hip/hip_runtime.h>
#include <hip/hip_fp16.h>

#define IMGS 32
#define H 512
#define W 512
#define NPIX (H * W)            // 262144
#define NTHR 256
#define RB 16                   // rows per band (k1)
#define NBANDS (H / RB)         // 32 bands per image
#define C4W (W / 4)             // 128 float4 per row
#define NBLK1 (IMGS * NBANDS)   // 1024 blocks for k1
#define NBLK2 4096              // k2: 8 px/thread -> 4096 blocks
#define PXB2 (NTHR * 8)         // 2048 px per k2 block

typedef float vfloat4 __attribute__((ext_vector_type(4)));  // for nt-store

// Combined 9-pt stencil (sum_j 2^j/15 = 1 collapses the 4 directional LTPE
// kernels + recombination into one stencil):
// s = 0.5*g - 0.25*(c0(L+R)+c1(UR+DL)+c2(U+D)+c3(UL+DR)) + 0.5
__device__ __forceinline__ float sten(float C, float L, float R, float U, float D,
                                      float UL, float UR, float DL, float DR) {
    const float c0 = 1.0f / 15.0f, c1 = 2.0f / 15.0f;
    const float c2 = 4.0f / 15.0f, c3 = 8.0f / 15.0f;
    const float acc = c0 * (L + R) + c1 * (UR + DL) + c2 * (U + D) + c3 * (UL + DR);
    return fmaf(-0.25f, acc, fmaf(0.5f, C, 0.5f));
}

// K1: 512x16 band per block (grid = 1024). Stage 18 gray halo rows in LDS
// (coalesced float4), stencil via rolling rows, write s as fp16 into ws,
// one float2 (sum, sumsq) partial per block.
__global__ __launch_bounds__(NTHR) void k1_stencil(
    const float* __restrict__ x, __half* __restrict__ sout,
    float2* __restrict__ partials)
{
    __shared__ float G[RB + 2][W];       // 18 x 512 x 4B = 36.9 KB
    __shared__ float red[8];

    const int tid  = threadIdx.x;
    const int blk  = blockIdx.x;
    const int img  = blk >> 5;           // / NBANDS
    const int band = blk & (NBANDS - 1);
    const int r0   = band * RB;

    const float* xbase = x + (size_t)img * 3 * NPIX;
    __half* sbase = sout + (size_t)img * NPIX;

    // ---- stage gray halo rows r0-1 .. r0+16 (zero outside image) ----
#pragma unroll
    for (int it = 0; it < (RB + 2) * C4W / NTHR; ++it) {   // 9 iterations
        const int idx = it * NTHR + tid;                   // 0..2303
        const int ri  = idx >> 7;                          // 0..17
        const int c4  = idx & (C4W - 1);
        const int gr  = r0 - 1 + ri;
        float4 g4 = make_float4(0.f, 0.f, 0.f, 0.f);
        if ((unsigned)gr < (unsigned)H) {
            const float* p = xbase + gr * W + c4 * 4;
            const float4 r = *(const float4*)p;
            const float4 g = *(const float4*)(p + NPIX);
            const float4 b = *(const float4*)(p + 2 * NPIX);
            g4.x = fmaf(0.3f, r.x, fmaf(0.59f, g.x, 0.11f * b.x));
            g4.y = fmaf(0.3f, r.y, fmaf(0.59f, g.y, 0.11f * b.y));
            g4.z = fmaf(0.3f, r.z, fmaf(0.59f, g.z, 0.11f * b.z));
            g4.w = fmaf(0.3f, r.w, fmaf(0.59f, g.w, 0.11f * b.w));
        }
        *(float4*)&G[ri][c4 * 4] = g4;
    }
    __syncthreads();

    // ---- compute: thread = (half, c4); 8 rows per thread, rolling rows ----
    const int c4   = tid & (C4W - 1);
    const int half = tid >> 7;
    const int lr0  = half * (RB / 2);

    float sum = 0.0f, sq = 0.0f;

    float4 a4 = *(const float4*)&G[lr0][c4 * 4];
    float4 b4 = *(const float4*)&G[lr0 + 1][c4 * 4];
    float aL = (c4 == 0) ? 0.0f : G[lr0][c4 * 4 - 1];
    float aR = (c4 == C4W - 1) ? 0.0f : G[lr0][c4 * 4 + 4];
    float bL = (c4 == 0) ? 0.0f : G[lr0 + 1][c4 * 4 - 1];
    float bR = (c4 == C4W - 1) ? 0.0f : G[lr0 + 1][c4 * 4 + 4];

#pragma unroll
    for (int k = 0; k < RB / 2; ++k) {
        const int lr = lr0 + k + 2;            // row below
        const float4 d4 = *(const float4*)&G[lr][c4 * 4];
        const float dL = (c4 == 0) ? 0.0f : G[lr][c4 * 4 - 1];
        const float dR = (c4 == C4W - 1) ? 0.0f : G[lr][c4 * 4 + 4];

        float4 o;
        o.x = sten(b4.x, bL,   b4.y, a4.x, d4.x, aL,   a4.y, dL,   d4.y);
        o.y = sten(b4.y, b4.x, b4.z, a4.y, d4.y, a4.x, a4.z, d4.x, d4.z);
        o.z = sten(b4.z, b4.y, b4.w, a4.z, d4.z, a4.y, a4.w, d4.y, d4.w);
        o.w = sten(b4.w, b4.z, bR,   a4.w, d4.w, a4.z, aR,   d4.z, dR);

        sum += (o.x + o.y) + (o.z + o.w);
        sq = fmaf(o.x, o.x, sq); sq = fmaf(o.y, o.y, sq);
        sq = fmaf(o.z, o.z, sq); sq = fmaf(o.w, o.w, sq);

        union { __half h[4]; float2 f; } u;
        u.h[0] = __float2half_rn(o.x);
        u.h[1] = __float2half_rn(o.y);
        u.h[2] = __float2half_rn(o.z);
        u.h[3] = __float2half_rn(o.w);
        *(float2*)(sbase + (size_t)(r0 + half * (RB / 2) + k) * W + c4 * 4) = u.f;

        a4 = b4; aL = bL; aR = bR;
        b4 = d4; bL = dL; bR = dR;
    }

    // ---- block reduction of (sum, sq) ----
#pragma unroll
    for (int off = 32; off > 0; off >>= 1) {
        sum += __shfl_down(sum, off);
        sq  += __shfl_down(sq, off);
    }
    const int wave = tid >> 6;
    const int lane = tid & 63;
    if (lane == 0) { red[wave] = sum; red[4 + wave] = sq; }
    __syncthreads();
    if (tid == 0) {
        partials[blk] = make_float2((red[0] + red[1]) + (red[2] + red[3]),
                                    (red[4] + red[5]) + (red[6] + red[7]));
    }
}

// K2: per-image stats from the 32 band partials (block-redundant, L2-resident),
// then normalize s (8 px / thread, 16B loads) and nt-store 3 fp32 channels.
__global__ __launch_bounds__(NTHR) void k2_norm(
    const float2* __restrict__ partials, const __half* __restrict__ sin,
    float* __restrict__ out)
{
    __shared__ float sm[2];

    const int tid = threadIdx.x;
    const int blk = blockIdx.x;
    const int img = blk >> 7;            // 128 blocks per image
    const int bi  = blk & 127;

    if (tid < 64) {
        float S1 = 0.0f, S2 = 0.0f;
        if (tid < NBANDS) {              // NBANDS == 32
            const float2 p = partials[img * NBANDS + tid];
            S1 = p.x; S2 = p.y;
        }
#pragma unroll
        for (int off = 32; off > 0; off >>= 1) {
            S1 += __shfl_down(S1, off);
            S2 += __shfl_down(S2, off);
        }
        if (tid == 0) {
            const float m = S1 * (1.0f / NPIX);
            const float v = S2 * (1.0f / NPIX) - m * m;
            sm[0] = m;
            sm[1] = rsqrtf(v + 1e-5f);
        }
    }
    __syncthreads();
    const float mean = sm[0];
    const float rstd = sm[1];

    const __half* sb = sin + (size_t)img * NPIX;
    float* base = out + (size_t)img * 3 * NPIX;
    const size_t off = (size_t)(bi * NTHR + tid) * 8;   // 8 px per thread

    union { float4 f4; __half h[8]; } u;
    u.f4 = *(const float4*)(sb + off);

    vfloat4 v0, v1;
    v0.x = (__half2float(u.h[0]) - mean) * rstd;
    v0.y = (__half2float(u.h[1]) - mean) * rstd;
    v0.z = (__half2float(u.h[2]) - mean) * rstd;
    v0.w = (__half2float(u.h[3]) - mean) * rstd;
    v1.x = (__half2float(u.h[4]) - mean) * rstd;
    v1.y = (__half2float(u.h[5]) - mean) * rstd;
    v1.z = (__half2float(u.h[6]) - mean) * rstd;
    v1.w = (__half2float(u.h[7]) - mean) * rstd;

#pragma unroll
    for (int ch = 0; ch < 3; ++ch) {
        float* p = base + (size_t)ch * NPIX + off;
        __builtin_nontemporal_store(v0, (vfloat4*)p);
        __builtin_nontemporal_store(v1, (vfloat4*)(p + 4));
    }
}

extern "C" void kernel_launch(void* const* d_in, const int* in_sizes, int n_in,
                              void* d_out, int out_size, void* d_ws, size_t ws_size,
                              hipStream_t stream) {
    const float* x = (const float*)d_in[0];
    float* out = (float*)d_out;

    // ws layout: [s fp16: 32*262144*2 = 16 MiB | partials float2 x1024 = 8 KiB]
    __half* s = (__half*)d_ws;
    float2* partials = (float2*)((char*)d_ws + (size_t)IMGS * NPIX * sizeof(__half));

    k1_stencil<<<dim3(NBLK1), dim3(NTHR), 0, stream>>>(x, s, partials);
    k2_norm<<<dim3(NBLK2), dim3(NTHR), 0, stream>>>(partials, s, out);
}

// Round 8
// 45.621 us; speedup vs baseline: 1.3979x; 1.3979x over previous
//
#include <hip/hip_runtime.h>
#include <hip/hip_fp16.h>

#define IMGS 32
#define H 512
#define W 512
#define NPIX (H * W)            // 262144
#define NTHR 256
#define RB 8                    // rows per band
#define NBANDS (H / RB)         // 64 bands per image
#define C4W (W / 4)             // 128 float4 per row

typedef float vfloat4 __attribute__((ext_vector_type(4)));  // for nt-store

// Combined 9-pt stencil: s = 0.5*g - 0.25*(c0(L+R)+c1(UR+DL)+c2(U+D)+c3(UL+DR)) + 0.5
__device__ __forceinline__ float sten(float C, float L, float R, float U, float D,
                                      float UL, float UR, float DL, float DR) {
    const float c0 = 1.0f / 15.0f, c1 = 2.0f / 15.0f;
    const float c2 = 4.0f / 15.0f, c3 = 8.0f / 15.0f;
    const float acc = c0 * (L + R) + c1 * (UR + DL) + c2 * (U + D) + c3 * (UL + DR);
    return fmaf(-0.25f, acc, fmaf(0.5f, C, 0.5f));
}

// K1: full-width 512x8 band per block (grid = 32*64 = 2048 blocks, 20KB LDS ->
// 8 blocks/CU). Stage 10 gray rows via coalesced float4; rolling-row stencil;
// write s (fp16 in ws, or fp32 fallback); one float2 partial per block.
template <typename ST>
__global__ __launch_bounds__(NTHR, 6) void k1_stencil(
    const float* __restrict__ x, ST* sout, size_t sstride,
    float2* __restrict__ partials)
{
    __shared__ float G[RB + 2][W];       // 10 x 512 x 4B = 20 KB
    __shared__ float red[8];

    const int tid  = threadIdx.x;
    const int blk  = blockIdx.x;
    const int img  = blk >> 6;           // / NBANDS
    const int band = blk & (NBANDS - 1);
    const int r0   = band * RB;

    const float* xbase = x + (size_t)img * 3 * NPIX;
    ST* sbase = sout + (size_t)img * sstride;

    // ---- stage gray halo rows r0-1 .. r0+8 (zero outside image) ----
#pragma unroll
    for (int it = 0; it < (RB + 2) * C4W / NTHR; ++it) {   // 5 iterations
        const int idx = it * NTHR + tid;                   // 0..1279
        const int ri  = idx >> 7;                          // 0..9
        const int c4  = idx & (C4W - 1);
        const int gr  = r0 - 1 + ri;
        float4 g4 = make_float4(0.f, 0.f, 0.f, 0.f);
        if ((unsigned)gr < (unsigned)H) {
            const float* p = xbase + gr * W + c4 * 4;
            const float4 r = *(const float4*)p;
            const float4 g = *(const float4*)(p + NPIX);
            const float4 b = *(const float4*)(p + 2 * NPIX);
            g4.x = fmaf(0.3f, r.x, fmaf(0.59f, g.x, 0.11f * b.x));
            g4.y = fmaf(0.3f, r.y, fmaf(0.59f, g.y, 0.11f * b.y));
            g4.z = fmaf(0.3f, r.z, fmaf(0.59f, g.z, 0.11f * b.z));
            g4.w = fmaf(0.3f, r.w, fmaf(0.59f, g.w, 0.11f * b.w));
        }
        *(float4*)&G[ri][c4 * 4] = g4;
    }
    __syncthreads();

    // ---- compute: thread = (half, c4); RB/2 rows per thread, rolling ----
    const int c4   = tid & (C4W - 1);
    const int half = tid >> 7;                 // 0..1
    const int lr0  = half * (RB / 2);          // first LDS "above" row

    float sum = 0.0f, sq = 0.0f;

    float4 a4 = *(const float4*)&G[lr0][c4 * 4];
    float4 b4 = *(const float4*)&G[lr0 + 1][c4 * 4];
    float aL = (c4 == 0) ? 0.0f : G[lr0][c4 * 4 - 1];
    float aR = (c4 == C4W - 1) ? 0.0f : G[lr0][c4 * 4 + 4];
    float bL = (c4 == 0) ? 0.0f : G[lr0 + 1][c4 * 4 - 1];
    float bR = (c4 == C4W - 1) ? 0.0f : G[lr0 + 1][c4 * 4 + 4];

#pragma unroll
    for (int k = 0; k < RB / 2; ++k) {
        const int lr = lr0 + k + 2;            // row below
        const float4 d4 = *(const float4*)&G[lr][c4 * 4];
        const float dL = (c4 == 0) ? 0.0f : G[lr][c4 * 4 - 1];
        const float dR = (c4 == C4W - 1) ? 0.0f : G[lr][c4 * 4 + 4];

        float4 o;
        o.x = sten(b4.x, bL,   b4.y, a4.x, d4.x, aL,   a4.y, dL,   d4.y);
        o.y = sten(b4.y, b4.x, b4.z, a4.y, d4.y, a4.x, a4.z, d4.x, d4.z);
        o.z = sten(b4.z, b4.y, b4.w, a4.z, d4.z, a4.y, a4.w, d4.y, d4.w);
        o.w = sten(b4.w, b4.z, bR,   a4.w, d4.w, a4.z, aR,   d4.z, dR);

        sum += (o.x + o.y) + (o.z + o.w);
        sq = fmaf(o.x, o.x, sq); sq = fmaf(o.y, o.y, sq);
        sq = fmaf(o.z, o.z, sq); sq = fmaf(o.w, o.w, sq);

        const size_t off = (size_t)(r0 + half * (RB / 2) + k) * W + c4 * 4;
        if constexpr (sizeof(ST) == 2) {
            union { __half h[4]; float2 f; } u;
            u.h[0] = __float2half_rn(o.x);
            u.h[1] = __float2half_rn(o.y);
            u.h[2] = __float2half_rn(o.z);
            u.h[3] = __float2half_rn(o.w);
            *(float2*)(sbase + off) = u.f;     // cached: k2 re-reads s
        } else {
            *(float4*)(sbase + off) = o;
        }

        a4 = b4; aL = bL; aR = bR;
        b4 = d4; bL = dL; bR = dR;
    }

    // ---- block reduction ----
#pragma unroll
    for (int off = 32; off > 0; off >>= 1) {
        sum += __shfl_down(sum, off);
        sq  += __shfl_down(sq, off);
    }
    __syncthreads();                           // all LDS reads done
    const int wave = tid >> 6;
    const int lane = tid & 63;
    if (lane == 0) { red[wave] = sum; red[4 + wave] = sq; }
    __syncthreads();
    if (tid == 0) {
        partials[blk] = make_float2((red[0] + red[1]) + (red[2] + red[3]),
                                    (red[4] + red[5]) + (red[6] + red[7]));
    }
}

// K2: per-image stats from the 64 band partials (block-redundant, L2-resident),
// then normalize s and replicate to 3 fp32 channels. Out stores are
// NON-TEMPORAL (never re-read; preserves L2/L3 residence of x and s).
template <typename ST>
__global__ __launch_bounds__(NTHR) void k2_norm(
    const float2* __restrict__ partials, const ST* sin, size_t sstride,
    float* __restrict__ out)
{
    __shared__ float sm[2];

    const int tid = threadIdx.x;
    const int blk = blockIdx.x;
    const int img = blk >> 8;
    const int bi  = blk & 255;

    if (tid < 64) {
        const float2 p = partials[img * NBANDS + tid];   // NBANDS == 64
        float S1 = p.x, S2 = p.y;
#pragma unroll
        for (int off = 32; off > 0; off >>= 1) {
            S1 += __shfl_down(S1, off);
            S2 += __shfl_down(S2, off);
        }
        if (tid == 0) {
            const float m = S1 * (1.0f / NPIX);
            const float v = S2 * (1.0f / NPIX) - m * m;
            sm[0] = m;
            sm[1] = rsqrtf(v + 1e-5f);
        }
    }
    __syncthreads();
    const float mean = sm[0];
    const float rstd = sm[1];

    const ST* sb = sin + (size_t)img * sstride;
    float* base = out + (size_t)img * 3 * NPIX;
    const size_t off = (size_t)(bi * NTHR + tid) * 4;

    float4 v;
    if constexpr (sizeof(ST) == 2) {
        union { float2 f; __half h[4]; } u;
        u.f = *(const float2*)(sb + off);
        v.x = __half2float(u.h[0]); v.y = __half2float(u.h[1]);
        v.z = __half2float(u.h[2]); v.w = __half2float(u.h[3]);
    } else {
        v = *(const float4*)(sb + off);
    }
    vfloat4 o;
    o.x = (v.x - mean) * rstd;
    o.y = (v.y - mean) * rstd;
    o.z = (v.z - mean) * rstd;
    o.w = (v.w - mean) * rstd;
    __builtin_nontemporal_store(o, (vfloat4*)(base + off));
    __builtin_nontemporal_store(o, (vfloat4*)(base + NPIX + off));
    __builtin_nontemporal_store(o, (vfloat4*)(base + 2 * NPIX + off));
}

extern "C" void kernel_launch(void* const* d_in, const int* in_sizes, int n_in,
                              void* d_out, int out_size, void* d_ws, size_t ws_size,
                              hipStream_t stream) {
    const float* x = (const float*)d_in[0];
    float* out = (float*)d_out;

    const size_t s_bytes = (size_t)IMGS * NPIX * sizeof(__half);   // 16 MiB
    const size_t need = s_bytes + (size_t)IMGS * NBANDS * sizeof(float2);

    if (ws_size >= need) {
        __half* s = (__half*)d_ws;
        float2* partials = (float2*)((char*)d_ws + s_bytes);
        k1_stencil<__half><<<dim3(IMGS * NBANDS), dim3(NTHR), 0, stream>>>(
            x, s, (size_t)NPIX, partials);
        k2_norm<__half><<<dim3(IMGS * 256), dim3(NTHR), 0, stream>>>(
            partials, s, (size_t)NPIX, out);
    } else {
        // Fallback: fp32 s in out channel-0 plane (round-2 proven path).
        float2* partials = (float2*)d_ws;                          // 16 KiB
        k1_stencil<float><<<dim3(IMGS * NBANDS), dim3(NTHR), 0, stream>>>(
            x, out, (size_t)(3 * NPIX), partials);
        k2_norm<float><<<dim3(IMGS * 256), dim3(NTHR), 0, stream>>>(
            partials, out, (size_t)(3 * NPIX), out);
    }
}

// Round 9
// 45.493 us; speedup vs baseline: 1.4018x; 1.0028x over previous
//
#include <hip/hip_runtime.h>
#include <hip/hip_fp16.h>

#define IMGS 32
#define H 512
#define W 512
#define NPIX (H * W)            // 262144
#define NTHR 256
#define RB 8                    // rows per band
#define NBANDS (H / RB)         // 64 bands per image
#define C4W (W / 4)             // 128 float4 per row

typedef float vfloat4 __attribute__((ext_vector_type(4)));  // for nt-store

// Combined 9-pt stencil: s = 0.5*g - 0.25*(c0(L+R)+c1(UR+DL)+c2(U+D)+c3(UL+DR)) + 0.5
__device__ __forceinline__ float sten(float C, float L, float R, float U, float D,
                                      float UL, float UR, float DL, float DR) {
    const float c0 = 1.0f / 15.0f, c1 = 2.0f / 15.0f;
    const float c2 = 4.0f / 15.0f, c3 = 8.0f / 15.0f;
    const float acc = c0 * (L + R) + c1 * (UR + DL) + c2 * (U + D) + c3 * (UL + DR);
    return fmaf(-0.25f, acc, fmaf(0.5f, C, 0.5f));
}

// K1: full-width 512x8 band per block (grid = 32*64 = 2048 blocks, 20KB LDS ->
// 8 blocks/CU). Stage 10 gray rows via coalesced float4; rolling-row stencil;
// write s (fp16 in ws, or fp32 fallback); one float2 partial per block.
template <typename ST>
__global__ __launch_bounds__(NTHR, 6) void k1_stencil(
    const float* __restrict__ x, ST* sout, size_t sstride,
    float2* __restrict__ partials)
{
    __shared__ float G[RB + 2][W];       // 10 x 512 x 4B = 20 KB
    __shared__ float red[8];

    const int tid  = threadIdx.x;
    const int blk  = blockIdx.x;
    const int img  = blk >> 6;           // / NBANDS
    const int band = blk & (NBANDS - 1);
    const int r0   = band * RB;

    const float* xbase = x + (size_t)img * 3 * NPIX;
    ST* sbase = sout + (size_t)img * sstride;

    // ---- stage gray halo rows r0-1 .. r0+8 (zero outside image) ----
#pragma unroll
    for (int it = 0; it < (RB + 2) * C4W / NTHR; ++it) {   // 5 iterations
        const int idx = it * NTHR + tid;                   // 0..1279
        const int ri  = idx >> 7;                          // 0..9
        const int c4  = idx & (C4W - 1);
        const int gr  = r0 - 1 + ri;
        float4 g4 = make_float4(0.f, 0.f, 0.f, 0.f);
        if ((unsigned)gr < (unsigned)H) {
            const float* p = xbase + gr * W + c4 * 4;
            const float4 r = *(const float4*)p;
            const float4 g = *(const float4*)(p + NPIX);
            const float4 b = *(const float4*)(p + 2 * NPIX);
            g4.x = fmaf(0.3f, r.x, fmaf(0.59f, g.x, 0.11f * b.x));
            g4.y = fmaf(0.3f, r.y, fmaf(0.59f, g.y, 0.11f * b.y));
            g4.z = fmaf(0.3f, r.z, fmaf(0.59f, g.z, 0.11f * b.z));
            g4.w = fmaf(0.3f, r.w, fmaf(0.59f, g.w, 0.11f * b.w));
        }
        *(float4*)&G[ri][c4 * 4] = g4;
    }
    __syncthreads();

    // ---- compute: thread = (half, c4); RB/2 rows per thread, rolling ----
    const int c4   = tid & (C4W - 1);
    const int half = tid >> 7;                 // 0..1
    const int lr0  = half * (RB / 2);          // first LDS "above" row

    float sum = 0.0f, sq = 0.0f;

    float4 a4 = *(const float4*)&G[lr0][c4 * 4];
    float4 b4 = *(const float4*)&G[lr0 + 1][c4 * 4];
    float aL = (c4 == 0) ? 0.0f : G[lr0][c4 * 4 - 1];
    float aR = (c4 == C4W - 1) ? 0.0f : G[lr0][c4 * 4 + 4];
    float bL = (c4 == 0) ? 0.0f : G[lr0 + 1][c4 * 4 - 1];
    float bR = (c4 == C4W - 1) ? 0.0f : G[lr0 + 1][c4 * 4 + 4];

#pragma unroll
    for (int k = 0; k < RB / 2; ++k) {
        const int lr = lr0 + k + 2;            // row below
        const float4 d4 = *(const float4*)&G[lr][c4 * 4];
        const float dL = (c4 == 0) ? 0.0f : G[lr][c4 * 4 - 1];
        const float dR = (c4 == C4W - 1) ? 0.0f : G[lr][c4 * 4 + 4];

        float4 o;
        o.x = sten(b4.x, bL,   b4.y, a4.x, d4.x, aL,   a4.y, dL,   d4.y);
        o.y = sten(b4.y, b4.x, b4.z, a4.y, d4.y, a4.x, a4.z, d4.x, d4.z);
        o.z = sten(b4.z, b4.y, b4.w, a4.z, d4.z, a4.y, a4.w, d4.y, d4.w);
        o.w = sten(b4.w, b4.z, bR,   a4.w, d4.w, a4.z, aR,   d4.z, dR);

        sum += (o.x + o.y) + (o.z + o.w);
        sq = fmaf(o.x, o.x, sq); sq = fmaf(o.y, o.y, sq);
        sq = fmaf(o.z, o.z, sq); sq = fmaf(o.w, o.w, sq);

        const size_t off = (size_t)(r0 + half * (RB / 2) + k) * W + c4 * 4;
        if constexpr (sizeof(ST) == 2) {
            union { __half h[4]; float2 f; } u;
            u.h[0] = __float2half_rn(o.x);
            u.h[1] = __float2half_rn(o.y);
            u.h[2] = __float2half_rn(o.z);
            u.h[3] = __float2half_rn(o.w);
            *(float2*)(sbase + off) = u.f;     // cached: k2 re-reads s
        } else {
            *(float4*)(sbase + off) = o;
        }

        a4 = b4; aL = bL; aR = bR;
        b4 = d4; bL = dL; bR = dR;
    }

    // ---- block reduction ----
#pragma unroll
    for (int off = 32; off > 0; off >>= 1) {
        sum += __shfl_down(sum, off);
        sq  += __shfl_down(sq, off);
    }
    __syncthreads();                           // all LDS reads done
    const int wave = tid >> 6;
    const int lane = tid & 63;
    if (lane == 0) { red[wave] = sum; red[4 + wave] = sq; }
    __syncthreads();
    if (tid == 0) {
        partials[blk] = make_float2((red[0] + red[1]) + (red[2] + red[3]),
                                    (red[4] + red[5]) + (red[6] + red[7]));
    }
}

// K2: per-image stats from the 64 band partials (block-redundant, L2-resident),
// then normalize s and replicate to 3 fp32 channels (nt-stores, never re-read).
// Block mapping is XCD-aligned with k1: k2 block m handles quarter r of k1
// band q, with m%8 == q%8, so the s read hits the L2 of the XCD that wrote it.
// m = (q>>3)<<5 | r<<3 | (q&7)  (bijective on [0,8192))
template <typename ST>
__global__ __launch_bounds__(NTHR) void k2_norm(
    const float2* __restrict__ partials, const ST* sin, size_t sstride,
    float* __restrict__ out)
{
    __shared__ float sm[2];

    const int tid  = threadIdx.x;
    const int b    = blockIdx.x;
    const int xcd  = b & 7;
    const int r    = (b >> 3) & 3;               // quarter within band
    const int q    = ((b >> 5) << 3) | xcd;      // k1 block id [0,2048)
    const int img  = q >> 6;
    const int band = q & (NBANDS - 1);

    if (tid < 64) {
        const float2 p = partials[img * NBANDS + tid];   // NBANDS == 64
        float S1 = p.x, S2 = p.y;
#pragma unroll
        for (int off = 32; off > 0; off >>= 1) {
            S1 += __shfl_down(S1, off);
            S2 += __shfl_down(S2, off);
        }
        if (tid == 0) {
            const float m = S1 * (1.0f / NPIX);
            const float v = S2 * (1.0f / NPIX) - m * m;
            sm[0] = m;
            sm[1] = rsqrtf(v + 1e-5f);
        }
    }
    __syncthreads();
    const float mean = sm[0];
    const float rstd = sm[1];

    const ST* sb = sin + (size_t)img * sstride;
    float* base = out + (size_t)img * 3 * NPIX;
    // quarter-band pixel range: band*4096 + r*1024 + tid*4
    const size_t off = (size_t)band * (RB * W) + (size_t)r * (NTHR * 4) + tid * 4;

    float4 v;
    if constexpr (sizeof(ST) == 2) {
        union { float2 f; __half h[4]; } u;
        u.f = *(const float2*)(sb + off);
        v.x = __half2float(u.h[0]); v.y = __half2float(u.h[1]);
        v.z = __half2float(u.h[2]); v.w = __half2float(u.h[3]);
    } else {
        v = *(const float4*)(sb + off);
    }
    vfloat4 o;
    o.x = (v.x - mean) * rstd;
    o.y = (v.y - mean) * rstd;
    o.z = (v.z - mean) * rstd;
    o.w = (v.w - mean) * rstd;
    __builtin_nontemporal_store(o, (vfloat4*)(base + off));
    __builtin_nontemporal_store(o, (vfloat4*)(base + NPIX + off));
    __builtin_nontemporal_store(o, (vfloat4*)(base + 2 * NPIX + off));
}

extern "C" void kernel_launch(void* const* d_in, const int* in_sizes, int n_in,
                              void* d_out, int out_size, void* d_ws, size_t ws_size,
                              hipStream_t stream) {
    const float* x = (const float*)d_in[0];
    float* out = (float*)d_out;

    const size_t s_bytes = (size_t)IMGS * NPIX * sizeof(__half);   // 16 MiB
    const size_t need = s_bytes + (size_t)IMGS * NBANDS * sizeof(float2);

    if (ws_size >= need) {
        __half* s = (__half*)d_ws;
        float2* partials = (float2*)((char*)d_ws + s_bytes);
        k1_stencil<__half><<<dim3(IMGS * NBANDS), dim3(NTHR), 0, stream>>>(
            x, s, (size_t)NPIX, partials);
        k2_norm<__half><<<dim3(IMGS * 256), dim3(NTHR), 0, stream>>>(
            partials, s, (size_t)NPIX, out);
    } else {
        // Fallback: fp32 s in out channel-0 plane (round-2 proven path).
        float2* partials = (float2*)d_ws;                          // 16 KiB
        k1_stencil<float><<<dim3(IMGS * NBANDS), dim3(NTHR), 0, stream>>>(
            x, out, (size_t)(3 * NPIX), partials);
        k2_norm<float><<<dim3(IMGS * 256), dim3(NTHR), 0, stream>>>(
            partials, out, (size_t)(3 * NPIX), out);
    }
}